// Round 7
// baseline (947.557 us; speedup 1.0000x reference)
//
#include <hip/hip_runtime.h>
#include <math.h>

#define F_IN 128
#define NHD 8
#define FEAT 128   // NHD*FO
#define NEG_SLOPE 0.2f
#define LN_EPS 1e-5f
#define BSH 6      // 64 nodes per bucket
#define BMSK 63
#define NPB 64
#define BCAP 2048  // bucket capacity (mean ~1088 for this graph; +29 sigma)
#define EPB 4096   // edges binned per phase-A block (512 thr x 8)

typedef __bf16 v8bf __attribute__((ext_vector_type(8)));
typedef __bf16 v2bf __attribute__((ext_vector_type(2)));
typedef float f32x4 __attribute__((ext_vector_type(4)));

// transpose + cast W: WT[c][k] = bf16(W[k][c])
__global__ __launch_bounds__(256) void k_wt(const float* __restrict__ W,
                                            __bf16* __restrict__ WT) {
    int idx = blockIdx.x * 256 + threadIdx.x;   // 16384 total
    int k = idx >> 7, c = idx & 127;
    WT[c * 128 + k] = (__bf16)W[idx];
}

// Fused: blocks [0,Ga) = phase-A binning (first: it's the long pole);
// blocks [Ga,..) = MFMA GEMM (+att-logit epilogue).
__global__ __launch_bounds__(512) void k_fused(const float* __restrict__ x,
                                               const __bf16* __restrict__ WT,
                                               const float* __restrict__ att_src,
                                               const float* __restrict__ att_dst,
                                               __bf16* __restrict__ xp16,
                                               float* __restrict__ a_src,
                                               float* __restrict__ a_dst,
                                               const int* __restrict__ src,
                                               const int* __restrict__ dst,
                                               int* __restrict__ bcur,
                                               unsigned int* __restrict__ buckets,
                                               int n, int E, int Ga) {
    if ((int)blockIdx.x < Ga) {
        // ---- phase A: bin 4096 edges by dst>>BSH; edges kept in registers ----
        __shared__ int lcnt[1024];
        __shared__ int lcur[1024];
        int NB = (n + BMSK) >> BSH;
        int tid = threadIdx.x;
        long base0 = (long)blockIdx.x * EPB;
        int total = E + n;
        for (int b = tid; b < NB; b += 512) lcnt[b] = 0;
        __syncthreads();
        int s0[8], d0[8];
        bool val[8];
        long e0 = base0 + (long)tid * 8;
        if (e0 + 7 < E) {
            int4 sa = *(const int4*)(src + e0);
            int4 sb = *(const int4*)(src + e0 + 4);
            int4 da = *(const int4*)(dst + e0);
            int4 db = *(const int4*)(dst + e0 + 4);
            s0[0] = sa.x; s0[1] = sa.y; s0[2] = sa.z; s0[3] = sa.w;
            s0[4] = sb.x; s0[5] = sb.y; s0[6] = sb.z; s0[7] = sb.w;
            d0[0] = da.x; d0[1] = da.y; d0[2] = da.z; d0[3] = da.w;
            d0[4] = db.x; d0[5] = db.y; d0[6] = db.z; d0[7] = db.w;
#pragma unroll
            for (int j = 0; j < 8; ++j) val[j] = true;
        } else {
#pragma unroll
            for (int j = 0; j < 8; ++j) {
                long e = e0 + j;
                val[j] = (e < total);
                s0[j] = d0[j] = 0;
                if (val[j]) {
                    if (e < E) { s0[j] = src[e]; d0[j] = dst[e]; }
                    else { s0[j] = d0[j] = (int)(e - E); }
                }
            }
        }
#pragma unroll
        for (int j = 0; j < 8; ++j)
            if (val[j]) atomicAdd(&lcnt[d0[j] >> BSH], 1);
        __syncthreads();
        for (int b = tid; b < NB; b += 512) {
            int c = lcnt[b];
            lcur[b] = c ? atomicAdd(&bcur[b], c) : 0;   // reserve global range
        }
        __syncthreads();
#pragma unroll
        for (int j = 0; j < 8; ++j) {
            if (val[j]) {
                int b = d0[j] >> BSH;
                int pos = atomicAdd(&lcur[b], 1);
                if (pos < BCAP)
                    buckets[(long)b * BCAP + pos] =
                        ((unsigned)s0[j] << BSH) | (unsigned)(d0[j] & BMSK);
            }
        }
    } else {
        // ---- GEMM path: 8 waves, wave = head (16-col tile), 16 rows/block ----
        int gb = blockIdx.x - Ga;
        int wv = threadIdx.x >> 6;
        int lane = threadIdx.x & 63;
        int m = lane & 15, quad = lane >> 4;
        int rowbase = gb * 16;
        int colbase = wv * 16;
        int rm = rowbase + m; if (rm > n - 1) rm = n - 1;
        f32x4 acc = {0.f, 0.f, 0.f, 0.f};
        const float* xrow = x + (long)rm * 128;
        const __bf16* wcol = WT + (colbase + m) * 128;
#pragma unroll
        for (int kk = 0; kk < 4; ++kk) {
            int kb = kk * 32 + quad * 8;
            float4 xa = *(const float4*)(xrow + kb);
            float4 xb = *(const float4*)(xrow + kb + 4);
            v8bf a;
            a[0] = (__bf16)xa.x; a[1] = (__bf16)xa.y; a[2] = (__bf16)xa.z; a[3] = (__bf16)xa.w;
            a[4] = (__bf16)xb.x; a[5] = (__bf16)xb.y; a[6] = (__bf16)xb.z; a[7] = (__bf16)xb.w;
            v8bf b = *(const v8bf*)(wcol + kb);
            acc = __builtin_amdgcn_mfma_f32_16x16x32_bf16(a, b, acc, 0, 0, 0);
        }
        float ws = att_src[colbase + m];
        float wd = att_dst[colbase + m];
#pragma unroll
        for (int r = 0; r < 4; ++r) {
            int row = rowbase + quad * 4 + r;
            float ts = acc[r] * ws;
            float td = acc[r] * wd;
#pragma unroll
            for (int o = 1; o < 16; o <<= 1) {
                ts += __shfl_xor(ts, o);
                td += __shfl_xor(td, o);
            }
            if (row < n) {
                xp16[(long)row * 128 + colbase + m] = (__bf16)acc[r];
                if (m == 0) {
                    a_src[row * 8 + wv] = ts;
                    a_dst[row * 8 + wv] = td;
                }
            }
        }
    }
}

// One block per 64-node bucket: stream packed entries, accumulate softmax-
// weighted messages into LDS, then LayerNorm + store. No slot table.
__global__ __launch_bounds__(512) void k_agg2(const unsigned int* __restrict__ buckets,
                                              const int* __restrict__ bcur,
                                              const float* __restrict__ a_src,
                                              const float* __restrict__ a_dst,
                                              const __bf16* __restrict__ xp16,
                                              const float* __restrict__ bias,
                                              const float* __restrict__ gamma,
                                              const float* __restrict__ beta,
                                              const int* __restrict__ src,
                                              const int* __restrict__ dst,
                                              float* __restrict__ out, int n, int E) {
    __shared__ float accs[NPB * FEAT];    // 32 KB
    __shared__ float zs[NPB * NHD];       // 2 KB
    __shared__ float adst_s[NPB * NHD];   // 2 KB
    int b = blockIdx.x;
    int tid = threadIdx.x;
    int node0 = b << BSH;
    int nloc = n - node0; if (nloc > NPB) nloc = NPB;
    for (int i = tid; i < NPB * FEAT; i += 512) accs[i] = 0.f;
    for (int i = tid; i < NPB * NHD; i += 512) {
        zs[i] = 0.f;
        int nd = node0 + (i >> 3);
        adst_s[i] = (nd < n) ? a_dst[nd * NHD + (i & 7)] : 0.f;
    }
    __syncthreads();
    int cnt = bcur[b];
    int lane = tid & 63, wv = tid >> 6;
    int h = lane & 7, j8 = lane >> 3;

    if (cnt <= BCAP) {
        const unsigned int* row = buckets + (long)b * BCAP;
        for (int base = wv * 8; base < cnt; base += 64) {
            int idx = base + j8;
            int cl = idx < cnt ? idx : cnt - 1;
            unsigned int u = row[cl];
            int s_my = (int)(u >> BSH), dl_my = (int)(u & BMSK);
            float e = a_src[s_my * NHD + h] + adst_s[dl_my * NHD + h];
            e = e > 0.f ? e : NEG_SLOPE * e;
            float w_my = (idx < cnt) ? __expf(e) : 0.f;
            if (w_my != 0.f) atomicAdd(&zs[dl_my * NHD + h], w_my);
#pragma unroll
            for (int j = 0; j < 8; ++j) {
                int sj = __shfl(s_my, j * 8);
                int dlj = __shfl(dl_my, j * 8);
                float wj = __shfl(w_my, j * 8 + j8);
                v2bf p = *(const v2bf*)(xp16 + (long)sj * FEAT + 2 * lane);
                atomicAdd(&accs[dlj * FEAT + 2 * lane], wj * (float)p[0]);
                atomicAdd(&accs[dlj * FEAT + 2 * lane + 1], wj * (float)p[1]);
            }
        }
    } else {
        // ---- overflow fallback (never expected): scan full edge list ----
        long total = (long)E + n;
        for (long base = (long)wv * 64; base < total; base += 512) {
            long e = base + lane;
            bool mt = false; int sv = 0, dv = 0;
            if (e < total) {
                if (e < E) { sv = src[e]; dv = dst[e]; }
                else { sv = dv = (int)(e - E); }
                mt = ((dv >> BSH) == b);
            }
            unsigned long long mask = __ballot(mt);
            while (mask) {
                int bl = __ffsll((unsigned long long)mask) - 1;
                mask &= mask - 1;
                int s = __shfl(sv, bl);
                int dl = __shfl(dv, bl) & BMSK;
                float eh = a_src[s * NHD + h] + adst_s[dl * NHD + h];
                eh = eh > 0.f ? eh : NEG_SLOPE * eh;
                float we = __expf(eh);
                if (lane < 8) atomicAdd(&zs[dl * NHD + lane], __shfl(we, lane));
                float w = __shfl(we, j8);
                v2bf p = *(const v2bf*)(xp16 + (long)s * FEAT + 2 * lane);
                atomicAdd(&accs[dl * FEAT + 2 * lane], w * (float)p[0]);
                atomicAdd(&accs[dl * FEAT + 2 * lane + 1], w * (float)p[1]);
            }
        }
    }
    __syncthreads();

    // ---- epilogue: normalize, bias, LayerNorm, store (8 nodes per wave) ----
    float2 bs = *(const float2*)(bias + 2 * lane);
    float2 g  = *(const float2*)(gamma + 2 * lane);
    float2 bt = *(const float2*)(beta + 2 * lane);
    for (int i = wv; i < nloc; i += 8) {
        int node = node0 + i;
        float inv = 1.f / zs[i * NHD + j8];
        float v0 = accs[i * FEAT + 2 * lane] * inv + bs.x;
        float v1 = accs[i * FEAT + 2 * lane + 1] * inv + bs.y;
        float ssum = v0 + v1;
        float ssq = v0 * v0 + v1 * v1;
#pragma unroll
        for (int o = 32; o > 0; o >>= 1) {
            ssum += __shfl_xor(ssum, o);
            ssq += __shfl_xor(ssq, o);
        }
        float mu = ssum * (1.0f / FEAT);
        float var = ssq * (1.0f / FEAT) - mu * mu;
        float rs = rsqrtf(var + LN_EPS);
        float2 o2;
        o2.x = (v0 - mu) * rs * g.x + bt.x;
        o2.y = (v1 - mu) * rs * g.y + bt.y;
        *(float2*)(out + (long)node * FEAT + 2 * lane) = o2;
    }
}

extern "C" void kernel_launch(void* const* d_in, const int* in_sizes, int n_in,
                              void* d_out, int out_size, void* d_ws, size_t ws_size,
                              hipStream_t stream) {
    const float* x = (const float*)d_in[0];
    const int* edge_index = (const int*)d_in[1];
    const float* W = (const float*)d_in[2];
    const float* att_src = (const float*)d_in[3];
    const float* att_dst = (const float*)d_in[4];
    const float* bias = (const float*)d_in[5];
    const float* gamma = (const float*)d_in[6];
    const float* beta = (const float*)d_in[7];
    float* out = (float*)d_out;

    int n = in_sizes[0] / F_IN;
    int E = in_sizes[1] / 2;
    const int* src = edge_index;
    const int* dst = edge_index + E;
    int NB = (n + BMSK) >> BSH;

    char* ws = (char*)d_ws;
    __bf16* WT   = (__bf16*)ws;                    ws += (size_t)128 * 128 * 2;
    __bf16* xp16 = (__bf16*)ws;                    ws += (size_t)n * FEAT * 2;
    float* a_src = (float*)ws;                     ws += (size_t)n * NHD * 4;
    float* a_dst = (float*)ws;                     ws += (size_t)n * NHD * 4;
    int* bcur    = (int*)ws;                       ws += (size_t)1024 * 4;
    unsigned int* buckets = (unsigned int*)ws;     ws += (size_t)NB * BCAP * 4;

    hipMemsetAsync(bcur, 0, (size_t)NB * sizeof(int), stream);

    k_wt<<<64, 256, 0, stream>>>(W, WT);
    int Gg = (n + 15) / 16;
    int Ga = (E + n + EPB - 1) / EPB;
    k_fused<<<Ga + Gg, 512, 0, stream>>>(x, WT, att_src, att_dst, xp16, a_src, a_dst,
                                         src, dst, bcur, buckets, n, E, Ga);
    k_agg2<<<NB, 512, 0, stream>>>(buckets, bcur, a_src, a_dst, xp16,
                                   bias, gamma, beta, src, dst, out, n, E);
}

// Round 8
// 235.784 us; speedup vs baseline: 4.0188x; 4.0188x over previous
//
#include <hip/hip_runtime.h>
#include <math.h>

#define F_IN 128
#define NHD 8
#define FEAT 128   // NHD*FO
#define NEG_SLOPE 0.2f
#define LN_EPS 1e-5f
#define BSH 6      // 64 nodes per bucket
#define BMSK 63
#define NPB 64
#define NSEG 16    // segments per bucket (contention splitting)
#define SEGCAP 192 // mean ~68 entries/segment; +15 sigma
#define CAP 56     // per-node slot capacity in LDS; deg>CAP -> fallback
#define EPB 2048   // edges binned per phase-A block (512 thr x 4)

typedef __bf16 v8bf __attribute__((ext_vector_type(8)));
typedef __bf16 v2bf __attribute__((ext_vector_type(2)));
typedef float f32x4 __attribute__((ext_vector_type(4)));

// transpose + cast W: WT[c][k] = bf16(W[k][c])
__global__ __launch_bounds__(256) void k_wt(const float* __restrict__ W,
                                            __bf16* __restrict__ WT) {
    int idx = blockIdx.x * 256 + threadIdx.x;   // 16384 total
    int k = idx >> 7, c = idx & 127;
    WT[c * 128 + k] = (__bf16)W[idx];
}

// Fused: blocks [0,Ga) = reserve-free binning (no barriers, pipelined
// atomics); blocks [Ga,..) = MFMA GEMM (+att-logit epilogue).
__global__ __launch_bounds__(512) void k_fused(const float* __restrict__ x,
                                               const __bf16* __restrict__ WT,
                                               const float* __restrict__ att_src,
                                               const float* __restrict__ att_dst,
                                               __bf16* __restrict__ xp16,
                                               float* __restrict__ a_src,
                                               float* __restrict__ a_dst,
                                               const int* __restrict__ src,
                                               const int* __restrict__ dst,
                                               int* __restrict__ bcur,
                                               unsigned int* __restrict__ buckets,
                                               int n, int E, int Ga) {
    if ((int)blockIdx.x < Ga) {
        // ---- binning: direct atomic append into (bucket, segment) ----
        int tid = threadIdx.x;
        int rep = blockIdx.x & (NSEG - 1);
        long e0 = (long)blockIdx.x * EPB + (long)tid * 4;
        long total = (long)E + n;
        int s0[4], d0[4];
        bool val[4];
        if (e0 + 3 < E) {
            int4 sv = *(const int4*)(src + e0);
            int4 dv = *(const int4*)(dst + e0);
            s0[0] = sv.x; s0[1] = sv.y; s0[2] = sv.z; s0[3] = sv.w;
            d0[0] = dv.x; d0[1] = dv.y; d0[2] = dv.z; d0[3] = dv.w;
            val[0] = val[1] = val[2] = val[3] = true;
        } else {
#pragma unroll
            for (int j = 0; j < 4; ++j) {
                long e = e0 + j;
                val[j] = (e < total);
                s0[j] = d0[j] = 0;
                if (val[j]) {
                    if (e < E) { s0[j] = src[e]; d0[j] = dst[e]; }
                    else { s0[j] = d0[j] = (int)(e - E); }
                }
            }
        }
#pragma unroll
        for (int j = 0; j < 4; ++j) {
            if (val[j]) {
                int seg = (d0[j] >> BSH) * NSEG + rep;
                int pos = atomicAdd(&bcur[seg], 1);
                if (pos < SEGCAP)
                    buckets[(long)seg * SEGCAP + pos] =
                        ((unsigned)s0[j] << BSH) | (unsigned)(d0[j] & BMSK);
            }
        }
    } else {
        // ---- GEMM path: 8 waves, wave = head (16-col tile), 16 rows/block ----
        int gb = blockIdx.x - Ga;
        int wv = threadIdx.x >> 6;
        int lane = threadIdx.x & 63;
        int m = lane & 15, quad = lane >> 4;
        int rowbase = gb * 16;
        int colbase = wv * 16;
        int rm = rowbase + m; if (rm > n - 1) rm = n - 1;
        f32x4 acc = {0.f, 0.f, 0.f, 0.f};
        const float* xrow = x + (long)rm * 128;
        const __bf16* wcol = WT + (colbase + m) * 128;
#pragma unroll
        for (int kk = 0; kk < 4; ++kk) {
            int kb = kk * 32 + quad * 8;
            float4 xa = *(const float4*)(xrow + kb);
            float4 xb = *(const float4*)(xrow + kb + 4);
            v8bf a;
            a[0] = (__bf16)xa.x; a[1] = (__bf16)xa.y; a[2] = (__bf16)xa.z; a[3] = (__bf16)xa.w;
            a[4] = (__bf16)xb.x; a[5] = (__bf16)xb.y; a[6] = (__bf16)xb.z; a[7] = (__bf16)xb.w;
            v8bf b = *(const v8bf*)(wcol + kb);
            acc = __builtin_amdgcn_mfma_f32_16x16x32_bf16(a, b, acc, 0, 0, 0);
        }
        float ws = att_src[colbase + m];
        float wd = att_dst[colbase + m];
#pragma unroll
        for (int r = 0; r < 4; ++r) {
            int row = rowbase + quad * 4 + r;
            float ts = acc[r] * ws;
            float td = acc[r] * wd;
#pragma unroll
            for (int o = 1; o < 16; o <<= 1) {
                ts += __shfl_xor(ts, o);
                td += __shfl_xor(td, o);
            }
            if (row < n) {
                xp16[(long)row * 128 + colbase + m] = (__bf16)acc[r];
                if (m == 0) {
                    a_src[row * 8 + wv] = ts;
                    a_dst[row * 8 + wv] = td;
                }
            }
        }
    }
}

// One block per 64-node bucket: build per-node slot lists in LDS from the 16
// segments, then wave-per-node register aggregation + LayerNorm + store.
__global__ __launch_bounds__(512) void k_ba(const unsigned int* __restrict__ buckets,
                                            const int* __restrict__ bcur,
                                            const float* __restrict__ a_src,
                                            const float* __restrict__ a_dst,
                                            const __bf16* __restrict__ xp16,
                                            const float* __restrict__ bias,
                                            const float* __restrict__ gamma,
                                            const float* __restrict__ beta,
                                            const int* __restrict__ src,
                                            const int* __restrict__ dst,
                                            float* __restrict__ out, int n, int E) {
    __shared__ int slds[NPB * CAP];       // 14 KB slot lists
    __shared__ int lc[NPB];
    __shared__ float adst_s[NPB * NHD];   // 2 KB
    __shared__ int ovf;
    int b = blockIdx.x;
    int tid = threadIdx.x;
    int node0 = b << BSH;
    if (tid < NPB) lc[tid] = 0;
    if (tid == 0) ovf = 0;
    for (int i = tid; i < NPB * NHD; i += 512) {
        int nd = node0 + (i >> 3);
        adst_s[i] = (nd < n) ? a_dst[nd * NHD + (i & 7)] : 0.f;
    }
    __syncthreads();

    // ---- build: stream the 16 segments into LDS slot lists ----
    for (int seg = 0; seg < NSEG; ++seg) {
        int raw = bcur[b * NSEG + seg];
        int scnt = raw < SEGCAP ? raw : SEGCAP;
        if (raw > SEGCAP && tid == 0) ovf = 1;
        const unsigned int* srow = buckets + (long)(b * NSEG + seg) * SEGCAP;
        for (int i = tid; i < scnt; i += 512) {
            unsigned int u = srow[i];
            int dl = (int)(u & BMSK);
            int p = atomicAdd(&lc[dl], 1);
            if (p < CAP) slds[dl * CAP + p] = (int)(u >> BSH);
        }
    }
    __syncthreads();
    // pad each list to a multiple of 8 with dummy id 0 (weight forced to 0)
    if (tid < NPB) {
        int cc = lc[tid]; if (cc > CAP) cc = CAP;
        int pad = (cc + 7) & ~7; if (pad > CAP) pad = CAP;
        for (int p = cc; p < pad; ++p) slds[tid * CAP + p] = 0;
    }
    __syncthreads();

    int lane = tid & 63, wv = tid >> 6;
    int h = lane & 7, j8 = lane >> 3;
    int bovf = ovf;
    float2 bs = *(const float2*)(bias + 2 * lane);
    float2 g  = *(const float2*)(gamma + 2 * lane);
    float2 bt = *(const float2*)(beta + 2 * lane);

    // ---- aggregate: wave wv handles nodes wv, wv+8, ... ----
    for (int i = wv; i < NPB; i += 8) {
        int node = node0 + i;
        if (node >= n) break;
        int cnt = lc[i];
        float acc0 = 0.f, acc1 = 0.f, inv;

        if (!bovf && cnt <= CAP) {
            const int* row = slds + i * CAP;
            float b_h = adst_s[i * NHD + h];
            float zacc = 0.f;
            for (int base = 0; base < cnt; base += 8) {
                int s_my = row[base + j8];          // padded: always valid
                float e = a_src[s_my * NHD + h] + b_h;
                e = e > 0.f ? e : NEG_SLOPE * e;
                float w_my = (base + j8 < cnt) ? __expf(e) : 0.f;
                zacc += w_my;
                int ss[8];
#pragma unroll
                for (int j = 0; j < 8; ++j) ss[j] = row[base + j];   // broadcast
                float2 vals[8];
#pragma unroll
                for (int j = 0; j < 8; ++j) {
                    v2bf p = *(const v2bf*)(xp16 + (long)ss[j] * FEAT + 2 * lane);
                    vals[j] = make_float2((float)p[0], (float)p[1]);
                }
#pragma unroll
                for (int j = 0; j < 8; ++j) {
                    float w = __shfl(w_my, j * 8 + j8);
                    acc0 = fmaf(w, vals[j].x, acc0);
                    acc1 = fmaf(w, vals[j].y, acc1);
                }
            }
            zacc += __shfl_xor(zacc, 8);
            zacc += __shfl_xor(zacc, 16);
            zacc += __shfl_xor(zacc, 32);
            float z = __shfl(zacc, j8);
            inv = 1.f / z;
        } else {
            // ---- fallback (overflow; never expected): rescan edge list ----
            float b_h = a_dst[node * NHD + j8];
            float z = 0.f;
            {   // self-loop
                float e = a_src[node * NHD + j8] + b_h;
                e = e > 0.f ? e : NEG_SLOPE * e;
                float w = __expf(e);
                z += w;
                v2bf p = *(const v2bf*)(xp16 + (long)node * FEAT + 2 * lane);
                acc0 = fmaf(w, (float)p[0], acc0);
                acc1 = fmaf(w, (float)p[1], acc1);
            }
            for (int base = 0; base < E; base += 64) {
                int e = base + lane;
                int sv = 0;
                bool mt = false;
                if (e < E) { mt = (dst[e] == node); if (mt) sv = src[e]; }
                unsigned long long mask = __ballot(mt);
                while (mask) {
                    int bl = __ffsll(mask) - 1;
                    mask &= mask - 1;
                    int s = __shfl(sv, bl);
                    float ee = a_src[s * NHD + j8] + b_h;
                    ee = ee > 0.f ? ee : NEG_SLOPE * ee;
                    float w = __expf(ee);
                    z += w;
                    v2bf p = *(const v2bf*)(xp16 + (long)s * FEAT + 2 * lane);
                    acc0 = fmaf(w, (float)p[0], acc0);
                    acc1 = fmaf(w, (float)p[1], acc1);
                }
            }
            inv = 1.f / z;
        }

        // ---- epilogue: normalize, bias, LayerNorm, store ----
        float v0 = acc0 * inv + bs.x;
        float v1 = acc1 * inv + bs.y;
        float ssum = v0 + v1;
        float ssq = v0 * v0 + v1 * v1;
#pragma unroll
        for (int o = 32; o > 0; o >>= 1) {
            ssum += __shfl_xor(ssum, o);
            ssq += __shfl_xor(ssq, o);
        }
        float mu = ssum * (1.0f / FEAT);
        float var = ssq * (1.0f / FEAT) - mu * mu;
        float rs = rsqrtf(var + LN_EPS);
        float2 o2;
        o2.x = (v0 - mu) * rs * g.x + bt.x;
        o2.y = (v1 - mu) * rs * g.y + bt.y;
        *(float2*)(out + (long)node * FEAT + 2 * lane) = o2;
    }
}

extern "C" void kernel_launch(void* const* d_in, const int* in_sizes, int n_in,
                              void* d_out, int out_size, void* d_ws, size_t ws_size,
                              hipStream_t stream) {
    const float* x = (const float*)d_in[0];
    const int* edge_index = (const int*)d_in[1];
    const float* W = (const float*)d_in[2];
    const float* att_src = (const float*)d_in[3];
    const float* att_dst = (const float*)d_in[4];
    const float* bias = (const float*)d_in[5];
    const float* gamma = (const float*)d_in[6];
    const float* beta = (const float*)d_in[7];
    float* out = (float*)d_out;

    int n = in_sizes[0] / F_IN;
    int E = in_sizes[1] / 2;
    const int* src = edge_index;
    const int* dst = edge_index + E;
    int NB = (n + BMSK) >> BSH;

    char* ws = (char*)d_ws;
    __bf16* WT   = (__bf16*)ws;                    ws += (size_t)128 * 128 * 2;
    __bf16* xp16 = (__bf16*)ws;                    ws += (size_t)n * FEAT * 2;
    float* a_src = (float*)ws;                     ws += (size_t)n * NHD * 4;
    float* a_dst = (float*)ws;                     ws += (size_t)n * NHD * 4;
    int* bcur    = (int*)ws;                       ws += (size_t)NB * NSEG * 4;
    unsigned int* buckets = (unsigned int*)ws;     ws += (size_t)NB * NSEG * SEGCAP * 4;

    hipMemsetAsync(bcur, 0, (size_t)NB * NSEG * sizeof(int), stream);

    k_wt<<<64, 256, 0, stream>>>(W, WT);
    int Gg = (n + 15) / 16;
    int Ga = (E + n + EPB - 1) / EPB;
    k_fused<<<Ga + Gg, 512, 0, stream>>>(x, WT, att_src, att_dst, xp16, a_src, a_dst,
                                         src, dst, bcur, buckets, n, E, Ga);
    k_ba<<<NB, 512, 0, stream>>>(buckets, bcur, a_src, a_dst, xp16,
                                 bias, gamma, beta, src, dst, out, n, E);
}

// Round 9
// 209.616 us; speedup vs baseline: 4.5204x; 1.1248x over previous
//
#include <hip/hip_runtime.h>
#include <math.h>

#define F_IN 128
#define NHD 8
#define FEAT 128   // NHD*FO
#define NEG_SLOPE 0.2f
#define LN_EPS 1e-5f
#define BSH 7      // 128 nodes per bucket
#define BMSK 127
#define NPB 128
#define CAP 48     // per-node slot capacity in LDS; deg>CAP -> fallback
#define EPB 2048   // edges sorted per phase-A block (512 thr x 4)
#define NBMAX 512  // max buckets (n <= 65536)

typedef __bf16 v8bf __attribute__((ext_vector_type(8)));
typedef __bf16 v2bf __attribute__((ext_vector_type(2)));
typedef float f32x4 __attribute__((ext_vector_type(4)));

// transpose + cast W: WT[c][k] = bf16(W[k][c])
__global__ __launch_bounds__(256) void k_wt(const float* __restrict__ W,
                                            __bf16* __restrict__ WT) {
    int idx = blockIdx.x * 256 + threadIdx.x;   // 16384 total
    int k = idx >> 7, c = idx & 127;
    WT[c * 128 + k] = (__bf16)W[idx];
}

// Fused: blocks [0,Ga) = block-local counting sort of 2048 edges by dst
// bucket (NO global atomics, fully coalesced output); blocks [Ga,..) =
// MFMA GEMM (+att-logit epilogue).
__global__ __launch_bounds__(512) void k_fused(const float* __restrict__ x,
                                               const __bf16* __restrict__ WT,
                                               const float* __restrict__ att_src,
                                               const float* __restrict__ att_dst,
                                               __bf16* __restrict__ xp16,
                                               float* __restrict__ a_src,
                                               float* __restrict__ a_dst,
                                               const int* __restrict__ src,
                                               const int* __restrict__ dst,
                                               unsigned int* __restrict__ sorted_g,
                                               int* __restrict__ runptr,
                                               int n, int E, int Ga) {
    if ((int)blockIdx.x < Ga) {
        // ---- phase A: block-local counting sort ----
        __shared__ int lcnt[NBMAX];
        __shared__ int loff[NBMAX + 1];
        __shared__ unsigned int sorted_l[EPB];
        __shared__ int wtot[8], wexcl[8];
        int NB = (n + BMSK) >> BSH;
        int tid = threadIdx.x, lane = tid & 63, wid = tid >> 6;
        long base0 = (long)blockIdx.x * EPB;
        long total = (long)E + n;
        if (tid < NB) lcnt[tid] = 0;
        __syncthreads();

        int s0[4], d0[4];
        bool val[4];
        long e0 = base0 + (long)tid * 4;
        if (e0 + 3 < E) {
            int4 sv = *(const int4*)(src + e0);
            int4 dv = *(const int4*)(dst + e0);
            s0[0] = sv.x; s0[1] = sv.y; s0[2] = sv.z; s0[3] = sv.w;
            d0[0] = dv.x; d0[1] = dv.y; d0[2] = dv.z; d0[3] = dv.w;
            val[0] = val[1] = val[2] = val[3] = true;
        } else {
#pragma unroll
            for (int j = 0; j < 4; ++j) {
                long e = e0 + j;
                val[j] = (e < total);
                s0[j] = d0[j] = 0;
                if (val[j]) {
                    if (e < E) { s0[j] = src[e]; d0[j] = dst[e]; }
                    else { s0[j] = d0[j] = (int)(e - E); }
                }
            }
        }
#pragma unroll
        for (int j = 0; j < 4; ++j)
            if (val[j]) atomicAdd(&lcnt[d0[j] >> BSH], 1);
        __syncthreads();

        // exclusive scan of lcnt[0..NB) (one elem per thread; NB <= 512)
        int v = (tid < NB) ? lcnt[tid] : 0;
        int xx = v;
#pragma unroll
        for (int o = 1; o < 64; o <<= 1) {
            int t2 = __shfl_up(xx, o);
            if (lane >= o) xx += t2;
        }
        if (lane == 63) wtot[wid] = xx;
        __syncthreads();
        if (wid == 0 && lane < 8) {
            int s = wtot[lane];
            int y = s;
#pragma unroll
            for (int o = 1; o < 8; o <<= 1) {
                int t2 = __shfl_up(y, o);
                if (lane >= o) y += t2;
            }
            wexcl[lane] = y - s;
        }
        __syncthreads();
        int excl = wexcl[wid] + xx - v;
        if (tid < NB) loff[tid] = excl;
        if (tid == NB - 1) loff[NB] = excl + v;
        __syncthreads();
        if (tid < NB) lcnt[tid] = loff[tid];   // cursor
        __syncthreads();
#pragma unroll
        for (int j = 0; j < 4; ++j) {
            if (val[j]) {
                int b = d0[j] >> BSH;
                int pos = atomicAdd(&lcnt[b], 1);
                sorted_l[pos] = ((unsigned)s0[j] << BSH) | (unsigned)(d0[j] & BMSK);
            }
        }
        __syncthreads();
        int tv = loff[NB];
        for (int i = tid; i < tv; i += 512)
            sorted_g[base0 + i] = sorted_l[i];
        if (tid <= NB) runptr[(long)blockIdx.x * (NBMAX + 1) + tid] = loff[tid];
    } else {
        // ---- GEMM path: 8 waves, wave = head (16-col tile), 16 rows/block ----
        int gb = blockIdx.x - Ga;
        int wv = threadIdx.x >> 6;
        int lane = threadIdx.x & 63;
        int m = lane & 15, quad = lane >> 4;
        int rowbase = gb * 16;
        int colbase = wv * 16;
        int rm = rowbase + m; if (rm > n - 1) rm = n - 1;
        f32x4 acc = {0.f, 0.f, 0.f, 0.f};
        const float* xrow = x + (long)rm * 128;
        const __bf16* wcol = WT + (colbase + m) * 128;
#pragma unroll
        for (int kk = 0; kk < 4; ++kk) {
            int kb = kk * 32 + quad * 8;
            float4 xa = *(const float4*)(xrow + kb);
            float4 xb = *(const float4*)(xrow + kb + 4);
            v8bf a;
            a[0] = (__bf16)xa.x; a[1] = (__bf16)xa.y; a[2] = (__bf16)xa.z; a[3] = (__bf16)xa.w;
            a[4] = (__bf16)xb.x; a[5] = (__bf16)xb.y; a[6] = (__bf16)xb.z; a[7] = (__bf16)xb.w;
            v8bf b = *(const v8bf*)(wcol + kb);
            acc = __builtin_amdgcn_mfma_f32_16x16x32_bf16(a, b, acc, 0, 0, 0);
        }
        float ws = att_src[colbase + m];
        float wd = att_dst[colbase + m];
#pragma unroll
        for (int r = 0; r < 4; ++r) {
            int row = rowbase + quad * 4 + r;
            float ts = acc[r] * ws;
            float td = acc[r] * wd;
#pragma unroll
            for (int o = 1; o < 16; o <<= 1) {
                ts += __shfl_xor(ts, o);
                td += __shfl_xor(td, o);
            }
            if (row < n) {
                xp16[(long)row * 128 + colbase + m] = (__bf16)acc[r];
                if (m == 0) {
                    a_src[row * 8 + wv] = ts;
                    a_dst[row * 8 + wv] = td;
                }
            }
        }
    }
}

// One block per 128-node bucket: gather this bucket's runs from all phase-A
// blocks into per-node LDS slot lists, then wave-per-node register
// aggregation + LayerNorm + store.
__global__ __launch_bounds__(512) void k_ba(const unsigned int* __restrict__ sorted_g,
                                            const int* __restrict__ runptr,
                                            const float* __restrict__ a_src,
                                            const float* __restrict__ a_dst,
                                            const __bf16* __restrict__ xp16,
                                            const float* __restrict__ bias,
                                            const float* __restrict__ gamma,
                                            const float* __restrict__ beta,
                                            const int* __restrict__ src,
                                            const int* __restrict__ dst,
                                            float* __restrict__ out, int n, int E, int Ga) {
    __shared__ int slds[NPB * CAP];       // 24 KB slot lists
    __shared__ int lc[NPB];
    __shared__ float adst_s[NPB * NHD];   // 4 KB
    int b = blockIdx.x;
    int tid = threadIdx.x;
    int node0 = b << BSH;
    if (tid < NPB) lc[tid] = 0;
    for (int i = tid; i < NPB * NHD; i += 512) {
        int nd = node0 + (i >> 3);
        adst_s[i] = (nd < n) ? a_dst[nd * NHD + (i & 7)] : 0.f;
    }
    __syncthreads();

    // ---- build: one thread per phase-A block, read its run for bucket b ----
    for (int blk = tid; blk < Ga; blk += 512) {
        const int* rp = runptr + (long)blk * (NBMAX + 1) + b;
        int st = rp[0], en = rp[1];
        const unsigned int* sg = sorted_g + (long)blk * EPB;
        for (int i = st; i < en; ++i) {
            unsigned int u = sg[i];
            int dl = (int)(u & BMSK);
            int p = atomicAdd(&lc[dl], 1);
            if (p < CAP) slds[dl * CAP + p] = (int)(u >> BSH);
        }
    }
    __syncthreads();
    // pad each list to a multiple of 8 with dummy id 0 (weight forced to 0)
    if (tid < NPB) {
        int cc = lc[tid]; if (cc > CAP) cc = CAP;
        int pad = (cc + 7) & ~7; if (pad > CAP) pad = CAP;
        for (int p = cc; p < pad; ++p) slds[tid * CAP + p] = 0;
    }
    __syncthreads();

    int lane = tid & 63, wv = tid >> 6;
    int h = lane & 7, j8 = lane >> 3;
    float2 bs = *(const float2*)(bias + 2 * lane);
    float2 g  = *(const float2*)(gamma + 2 * lane);
    float2 bt = *(const float2*)(beta + 2 * lane);

    // ---- aggregate: wave wv handles nodes wv, wv+8, ... ----
    for (int i = wv; i < NPB; i += 8) {
        int node = node0 + i;
        if (node >= n) break;
        int cnt = lc[i];
        float acc0 = 0.f, acc1 = 0.f, inv;

        if (cnt <= CAP) {
            const int* row = slds + i * CAP;
            float b_h = adst_s[i * NHD + h];
            float zacc = 0.f;
            for (int base = 0; base < cnt; base += 8) {
                int s_my = row[base + j8];          // padded: always valid
                float e = a_src[s_my * NHD + h] + b_h;
                e = e > 0.f ? e : NEG_SLOPE * e;
                float w_my = (base + j8 < cnt) ? __expf(e) : 0.f;
                zacc += w_my;
                int ss[8];
#pragma unroll
                for (int j = 0; j < 8; ++j) ss[j] = row[base + j];   // LDS broadcast
                float2 vals[8];
#pragma unroll
                for (int j = 0; j < 8; ++j) {
                    v2bf p = *(const v2bf*)(xp16 + (long)ss[j] * FEAT + 2 * lane);
                    vals[j] = make_float2((float)p[0], (float)p[1]);
                }
#pragma unroll
                for (int j = 0; j < 8; ++j) {
                    float w = __shfl(w_my, j * 8 + j8);
                    acc0 = fmaf(w, vals[j].x, acc0);
                    acc1 = fmaf(w, vals[j].y, acc1);
                }
            }
            zacc += __shfl_xor(zacc, 8);
            zacc += __shfl_xor(zacc, 16);
            zacc += __shfl_xor(zacc, 32);
            float z = __shfl(zacc, j8);
            inv = 1.f / z;
        } else {
            // ---- fallback (deg > CAP; never expected): rescan edge list ----
            float b_h = a_dst[node * NHD + j8];
            float z = 0.f;
            {   // self-loop
                float e = a_src[node * NHD + j8] + b_h;
                e = e > 0.f ? e : NEG_SLOPE * e;
                float w = __expf(e);
                z += w;
                v2bf p = *(const v2bf*)(xp16 + (long)node * FEAT + 2 * lane);
                acc0 = fmaf(w, (float)p[0], acc0);
                acc1 = fmaf(w, (float)p[1], acc1);
            }
            for (int base = 0; base < E; base += 64) {
                int e = base + lane;
                int sv = 0;
                bool mt = false;
                if (e < E) { mt = (dst[e] == node); if (mt) sv = src[e]; }
                unsigned long long mask = __ballot(mt);
                while (mask) {
                    int bl = __ffsll(mask) - 1;
                    mask &= mask - 1;
                    int s = __shfl(sv, bl);
                    float ee = a_src[s * NHD + j8] + b_h;
                    ee = ee > 0.f ? ee : NEG_SLOPE * ee;
                    float w = __expf(ee);
                    z += w;
                    v2bf p = *(const v2bf*)(xp16 + (long)s * FEAT + 2 * lane);
                    acc0 = fmaf(w, (float)p[0], acc0);
                    acc1 = fmaf(w, (float)p[1], acc1);
                }
            }
            inv = 1.f / z;
        }

        // ---- epilogue: normalize, bias, LayerNorm, store ----
        float v0 = acc0 * inv + bs.x;
        float v1 = acc1 * inv + bs.y;
        float ssum = v0 + v1;
        float ssq = v0 * v0 + v1 * v1;
#pragma unroll
        for (int o = 32; o > 0; o >>= 1) {
            ssum += __shfl_xor(ssum, o);
            ssq += __shfl_xor(ssq, o);
        }
        float mu = ssum * (1.0f / FEAT);
        float var = ssq * (1.0f / FEAT) - mu * mu;
        float rs = rsqrtf(var + LN_EPS);
        float2 o2;
        o2.x = (v0 - mu) * rs * g.x + bt.x;
        o2.y = (v1 - mu) * rs * g.y + bt.y;
        *(float2*)(out + (long)node * FEAT + 2 * lane) = o2;
    }
}

extern "C" void kernel_launch(void* const* d_in, const int* in_sizes, int n_in,
                              void* d_out, int out_size, void* d_ws, size_t ws_size,
                              hipStream_t stream) {
    const float* x = (const float*)d_in[0];
    const int* edge_index = (const int*)d_in[1];
    const float* W = (const float*)d_in[2];
    const float* att_src = (const float*)d_in[3];
    const float* att_dst = (const float*)d_in[4];
    const float* bias = (const float*)d_in[5];
    const float* gamma = (const float*)d_in[6];
    const float* beta = (const float*)d_in[7];
    float* out = (float*)d_out;

    int n = in_sizes[0] / F_IN;
    int E = in_sizes[1] / 2;
    const int* src = edge_index;
    const int* dst = edge_index + E;
    int NB = (n + BMSK) >> BSH;
    int Ga = (E + n + EPB - 1) / EPB;

    char* ws = (char*)d_ws;
    __bf16* WT   = (__bf16*)ws;                    ws += (size_t)128 * 128 * 2;
    __bf16* xp16 = (__bf16*)ws;                    ws += (size_t)n * FEAT * 2;
    float* a_src = (float*)ws;                     ws += (size_t)n * NHD * 4;
    float* a_dst = (float*)ws;                     ws += (size_t)n * NHD * 4;
    unsigned int* sorted_g = (unsigned int*)ws;    ws += (size_t)Ga * EPB * 4;
    int* runptr  = (int*)ws;                       ws += (size_t)Ga * (NBMAX + 1) * 4;

    k_wt<<<64, 256, 0, stream>>>(W, WT);
    int Gg = (n + 15) / 16;
    k_fused<<<Ga + Gg, 512, 0, stream>>>(x, WT, att_src, att_dst, xp16, a_src, a_dst,
                                         src, dst, sorted_g, runptr, n, E, Ga);
    k_ba<<<NB, 512, 0, stream>>>(sorted_g, runptr, a_src, a_dst, xp16,
                                 bias, gamma, beta, src, dst, out, n, E, Ga);
}

// Round 10
// 180.935 us; speedup vs baseline: 5.2370x; 1.1585x over previous
//
#include <hip/hip_runtime.h>
#include <math.h>

#define F_IN 128
#define NHD 8
#define FEAT 128   // NHD*FO
#define NEG_SLOPE 0.2f
#define LN_EPS 1e-5f
#define BSH 7      // 128 nodes per bucket
#define BMSK 127
#define NPQ 32     // nodes per k_ba block (quarter bucket)
#define CAP 48     // per-node slot capacity in LDS; deg>CAP -> fallback
#define EPB 2048   // edges sorted per phase-A block (512 thr x 4)
#define NBMAX 512  // max buckets (n <= 65536)

typedef __bf16 v8bf __attribute__((ext_vector_type(8)));
typedef __bf16 v2bf __attribute__((ext_vector_type(2)));
typedef float f32x4 __attribute__((ext_vector_type(4)));

// transpose + cast W: WT[c][k] = bf16(W[k][c])
__global__ __launch_bounds__(256) void k_wt(const float* __restrict__ W,
                                            __bf16* __restrict__ WT) {
    int idx = blockIdx.x * 256 + threadIdx.x;   // 16384 total
    int k = idx >> 7, c = idx & 127;
    WT[c * 128 + k] = (__bf16)W[idx];
}

// Fused: blocks [0,Ga) = block-local counting sort of 2048 edges by dst
// bucket (no global atomics, coalesced output); blocks [Ga,..) = MFMA GEMM
// with LDS-staged x tile (32 rows, 2 row-tiles per wave) + att epilogue.
__global__ __launch_bounds__(512) void k_fused(const float* __restrict__ x,
                                               const __bf16* __restrict__ WT,
                                               const float* __restrict__ att_src,
                                               const float* __restrict__ att_dst,
                                               __bf16* __restrict__ xp16,
                                               float* __restrict__ a_src,
                                               float* __restrict__ a_dst,
                                               const int* __restrict__ src,
                                               const int* __restrict__ dst,
                                               unsigned int* __restrict__ sorted_g,
                                               int* __restrict__ runptr,
                                               int n, int E, int Ga) {
    __shared__ __bf16 xs[32][136];        // 8.7 KB staged x tile (pad: stride 136)
    if ((int)blockIdx.x < Ga) {
        // ---- phase A: block-local counting sort ----
        __shared__ int lcnt[NBMAX];
        __shared__ int loff[NBMAX + 1];
        __shared__ unsigned int sorted_l[EPB];
        __shared__ int wtot[8], wexcl[8];
        int NB = (n + BMSK) >> BSH;
        int tid = threadIdx.x, lane = tid & 63, wid = tid >> 6;
        long base0 = (long)blockIdx.x * EPB;
        long total = (long)E + n;
        if (tid < NB) lcnt[tid] = 0;
        __syncthreads();

        int s0[4], d0[4];
        bool val[4];
        long e0 = base0 + (long)tid * 4;
        if (e0 + 3 < E) {
            int4 sv = *(const int4*)(src + e0);
            int4 dv = *(const int4*)(dst + e0);
            s0[0] = sv.x; s0[1] = sv.y; s0[2] = sv.z; s0[3] = sv.w;
            d0[0] = dv.x; d0[1] = dv.y; d0[2] = dv.z; d0[3] = dv.w;
            val[0] = val[1] = val[2] = val[3] = true;
        } else {
#pragma unroll
            for (int j = 0; j < 4; ++j) {
                long e = e0 + j;
                val[j] = (e < total);
                s0[j] = d0[j] = 0;
                if (val[j]) {
                    if (e < E) { s0[j] = src[e]; d0[j] = dst[e]; }
                    else { s0[j] = d0[j] = (int)(e - E); }
                }
            }
        }
#pragma unroll
        for (int j = 0; j < 4; ++j)
            if (val[j]) atomicAdd(&lcnt[d0[j] >> BSH], 1);
        __syncthreads();

        // exclusive scan of lcnt[0..NB) (one elem per thread; NB <= 512)
        int v = (tid < NB) ? lcnt[tid] : 0;
        int xx = v;
#pragma unroll
        for (int o = 1; o < 64; o <<= 1) {
            int t2 = __shfl_up(xx, o);
            if (lane >= o) xx += t2;
        }
        if (lane == 63) wtot[wid] = xx;
        __syncthreads();
        if (wid == 0 && lane < 8) {
            int s = wtot[lane];
            int y = s;
#pragma unroll
            for (int o = 1; o < 8; o <<= 1) {
                int t2 = __shfl_up(y, o);
                if (lane >= o) y += t2;
            }
            wexcl[lane] = y - s;
        }
        __syncthreads();
        int excl = wexcl[wid] + xx - v;
        if (tid < NB) loff[tid] = excl;
        if (tid == NB - 1) loff[NB] = excl + v;
        __syncthreads();
        if (tid < NB) lcnt[tid] = loff[tid];   // cursor
        __syncthreads();
#pragma unroll
        for (int j = 0; j < 4; ++j) {
            if (val[j]) {
                int b = d0[j] >> BSH;
                int pos = atomicAdd(&lcnt[b], 1);
                sorted_l[pos] = ((unsigned)s0[j] << BSH) | (unsigned)(d0[j] & BMSK);
            }
        }
        __syncthreads();
        int tv = loff[NB];
        for (int i = tid; i < tv; i += 512)
            sorted_g[base0 + i] = sorted_l[i];
        if (tid <= NB) runptr[(long)blockIdx.x * (NBMAX + 1) + tid] = loff[tid];
    } else {
        // ---- GEMM path: stage 32 x-rows to LDS (bf16), 8 waves = 8 heads,
        //      each wave does 2 row-tiles reusing its W fragments ----
        int gb = blockIdx.x - Ga;
        int tid = threadIdx.x;
        int rowbase = gb * 32;
        {   // cooperative stage: 1024 float4 over 512 threads
            int i4 = tid;
#pragma unroll
            for (int rep = 0; rep < 2; ++rep, i4 += 512) {
                int r = i4 >> 5, c4 = i4 & 31;
                int gr = rowbase + r; if (gr > n - 1) gr = n - 1;
                float4 xv = *(const float4*)(x + (long)gr * 128 + c4 * 4);
                __bf16* p = &xs[r][c4 * 4];
                p[0] = (__bf16)xv.x; p[1] = (__bf16)xv.y;
                p[2] = (__bf16)xv.z; p[3] = (__bf16)xv.w;
            }
        }
        __syncthreads();
        int wv = tid >> 6;
        int lane = tid & 63;
        int m = lane & 15, quad = lane >> 4;
        int colbase = wv * 16;
        const __bf16* wcol = WT + (colbase + m) * 128;
        v8bf wf[4];
#pragma unroll
        for (int kk = 0; kk < 4; ++kk)
            wf[kk] = *(const v8bf*)(wcol + kk * 32 + quad * 8);
        float ws = att_src[colbase + m];
        float wd = att_dst[colbase + m];
#pragma unroll
        for (int t = 0; t < 2; ++t) {
            int rb = t * 16;
            f32x4 acc = {0.f, 0.f, 0.f, 0.f};
#pragma unroll
            for (int kk = 0; kk < 4; ++kk) {
                v8bf a = *(const v8bf*)(&xs[rb + m][kk * 32 + quad * 8]);
                acc = __builtin_amdgcn_mfma_f32_16x16x32_bf16(a, wf[kk], acc, 0, 0, 0);
            }
#pragma unroll
            for (int r = 0; r < 4; ++r) {
                int row = rowbase + rb + quad * 4 + r;
                float ts = acc[r] * ws;
                float td = acc[r] * wd;
#pragma unroll
                for (int o = 1; o < 16; o <<= 1) {
                    ts += __shfl_xor(ts, o);
                    td += __shfl_xor(td, o);
                }
                if (row < n) {
                    xp16[(long)row * 128 + colbase + m] = (__bf16)acc[r];
                    if (m == 0) {
                        a_src[row * 8 + wv] = ts;
                        a_dst[row * 8 + wv] = td;
                    }
                }
            }
        }
    }
}

// 4 blocks per 128-node bucket (32 nodes each): gather this quarter's
// entries from all phase-A runs into LDS slot lists, then wave-per-node
// register aggregation + LayerNorm + store.
__global__ __launch_bounds__(256) void k_ba(const unsigned int* __restrict__ sorted_g,
                                            const int* __restrict__ runptr,
                                            const float* __restrict__ a_src,
                                            const float* __restrict__ a_dst,
                                            const __bf16* __restrict__ xp16,
                                            const float* __restrict__ bias,
                                            const float* __restrict__ gamma,
                                            const float* __restrict__ beta,
                                            const int* __restrict__ src,
                                            const int* __restrict__ dst,
                                            float* __restrict__ out, int n, int E, int Ga) {
    __shared__ int slds[NPQ * CAP];       // 6 KB slot lists
    __shared__ int lc[NPQ];
    __shared__ float adst_s[NPQ * NHD];   // 1 KB
    int b = blockIdx.x >> 2;
    int q = blockIdx.x & 3;
    int tid = threadIdx.x;
    int node0 = (b << BSH) + q * NPQ;
    if (tid < NPQ) lc[tid] = 0;
    if (tid < NPQ * NHD) {
        int nd = node0 + (tid >> 3);
        adst_s[tid] = (nd < n) ? a_dst[nd * NHD + (tid & 7)] : 0.f;
    }
    __syncthreads();

    // ---- build: one thread per phase-A block run; filter to this quarter ----
    int qlo = q * NPQ;
    for (int blk = tid; blk < Ga; blk += 256) {
        const int* rp = runptr + (long)blk * (NBMAX + 1) + b;
        int st = rp[0], en = rp[1];
        const unsigned int* sg = sorted_g + (long)blk * EPB;
        for (int i = st; i < en; ++i) {
            unsigned int u = sg[i];
            int dl = (int)(u & BMSK) - qlo;
            if ((unsigned)dl < NPQ) {
                int p = atomicAdd(&lc[dl], 1);
                if (p < CAP) slds[dl * CAP + p] = (int)(u >> BSH);
            }
        }
    }
    __syncthreads();
    // pad each list to a multiple of 8 with dummy id 0 (weight forced to 0)
    if (tid < NPQ) {
        int cc = lc[tid]; if (cc > CAP) cc = CAP;
        int pad = (cc + 7) & ~7; if (pad > CAP) pad = CAP;
        for (int p = cc; p < pad; ++p) slds[tid * CAP + p] = 0;
    }
    __syncthreads();

    int lane = tid & 63, wv = tid >> 6;
    int h = lane & 7, j8 = lane >> 3;
    float2 bs = *(const float2*)(bias + 2 * lane);
    float2 g  = *(const float2*)(gamma + 2 * lane);
    float2 bt = *(const float2*)(beta + 2 * lane);

    // ---- aggregate: wave wv handles nodes wv, wv+4, ... ----
    for (int i = wv; i < NPQ; i += 4) {
        int node = node0 + i;
        if (node >= n) break;
        int cnt = lc[i];
        float acc0 = 0.f, acc1 = 0.f, inv;

        if (cnt <= CAP) {
            const int* row = slds + i * CAP;
            float b_h = adst_s[i * NHD + h];
            float zacc = 0.f;
            for (int base = 0; base < cnt; base += 8) {
                int s_my = row[base + j8];          // padded: always valid
                float e = a_src[s_my * NHD + h] + b_h;
                e = e > 0.f ? e : NEG_SLOPE * e;
                float w_my = (base + j8 < cnt) ? __expf(e) : 0.f;
                zacc += w_my;
                int ss[8];
#pragma unroll
                for (int j = 0; j < 8; ++j) ss[j] = row[base + j];   // LDS broadcast
                float2 vals[8];
#pragma unroll
                for (int j = 0; j < 8; ++j) {
                    v2bf p = *(const v2bf*)(xp16 + (long)ss[j] * FEAT + 2 * lane);
                    vals[j] = make_float2((float)p[0], (float)p[1]);
                }
#pragma unroll
                for (int j = 0; j < 8; ++j) {
                    float w = __shfl(w_my, j * 8 + j8);
                    acc0 = fmaf(w, vals[j].x, acc0);
                    acc1 = fmaf(w, vals[j].y, acc1);
                }
            }
            zacc += __shfl_xor(zacc, 8);
            zacc += __shfl_xor(zacc, 16);
            zacc += __shfl_xor(zacc, 32);
            float z = __shfl(zacc, j8);
            inv = 1.f / z;
        } else {
            // ---- fallback (deg > CAP; never expected): rescan edge list ----
            float b_h = a_dst[node * NHD + j8];
            float z = 0.f;
            {   // self-loop
                float e = a_src[node * NHD + j8] + b_h;
                e = e > 0.f ? e : NEG_SLOPE * e;
                float w = __expf(e);
                z += w;
                v2bf p = *(const v2bf*)(xp16 + (long)node * FEAT + 2 * lane);
                acc0 = fmaf(w, (float)p[0], acc0);
                acc1 = fmaf(w, (float)p[1], acc1);
            }
            for (int base = 0; base < E; base += 64) {
                int e = base + lane;
                int sv = 0;
                bool mt = false;
                if (e < E) { mt = (dst[e] == node); if (mt) sv = src[e]; }
                unsigned long long mask = __ballot(mt);
                while (mask) {
                    int bl = __ffsll(mask) - 1;
                    mask &= mask - 1;
                    int s = __shfl(sv, bl);
                    float ee = a_src[s * NHD + j8] + b_h;
                    ee = ee > 0.f ? ee : NEG_SLOPE * ee;
                    float w = __expf(ee);
                    z += w;
                    v2bf p = *(const v2bf*)(xp16 + (long)s * FEAT + 2 * lane);
                    acc0 = fmaf(w, (float)p[0], acc0);
                    acc1 = fmaf(w, (float)p[1], acc1);
                }
            }
            inv = 1.f / z;
        }

        // ---- epilogue: normalize, bias, LayerNorm, store ----
        float v0 = acc0 * inv + bs.x;
        float v1 = acc1 * inv + bs.y;
        float ssum = v0 + v1;
        float ssq = v0 * v0 + v1 * v1;
#pragma unroll
        for (int o = 32; o > 0; o >>= 1) {
            ssum += __shfl_xor(ssum, o);
            ssq += __shfl_xor(ssq, o);
        }
        float mu = ssum * (1.0f / FEAT);
        float var = ssq * (1.0f / FEAT) - mu * mu;
        float rs = rsqrtf(var + LN_EPS);
        float2 o2;
        o2.x = (v0 - mu) * rs * g.x + bt.x;
        o2.y = (v1 - mu) * rs * g.y + bt.y;
        *(float2*)(out + (long)node * FEAT + 2 * lane) = o2;
    }
}

extern "C" void kernel_launch(void* const* d_in, const int* in_sizes, int n_in,
                              void* d_out, int out_size, void* d_ws, size_t ws_size,
                              hipStream_t stream) {
    const float* x = (const float*)d_in[0];
    const int* edge_index = (const int*)d_in[1];
    const float* W = (const float*)d_in[2];
    const float* att_src = (const float*)d_in[3];
    const float* att_dst = (const float*)d_in[4];
    const float* bias = (const float*)d_in[5];
    const float* gamma = (const float*)d_in[6];
    const float* beta = (const float*)d_in[7];
    float* out = (float*)d_out;

    int n = in_sizes[0] / F_IN;
    int E = in_sizes[1] / 2;
    const int* src = edge_index;
    const int* dst = edge_index + E;
    int NB = (n + BMSK) >> BSH;
    int Ga = (E + n + EPB - 1) / EPB;

    char* ws = (char*)d_ws;
    __bf16* WT   = (__bf16*)ws;                    ws += (size_t)128 * 128 * 2;
    __bf16* xp16 = (__bf16*)ws;                    ws += (size_t)n * FEAT * 2;
    float* a_src = (float*)ws;                     ws += (size_t)n * NHD * 4;
    float* a_dst = (float*)ws;                     ws += (size_t)n * NHD * 4;
    unsigned int* sorted_g = (unsigned int*)ws;    ws += (size_t)Ga * EPB * 4;
    int* runptr  = (int*)ws;                       ws += (size_t)Ga * (NBMAX + 1) * 4;

    k_wt<<<64, 256, 0, stream>>>(W, WT);
    int Gg = (n + 31) / 32;
    k_fused<<<Ga + Gg, 512, 0, stream>>>(x, WT, att_src, att_dst, xp16, a_src, a_dst,
                                         src, dst, sorted_g, runptr, n, E, Ga);
    k_ba<<<NB * 4, 256, 0, stream>>>(sorted_g, runptr, a_src, a_dst, xp16,
                                     bias, gamma, beta, src, dst, out, n, E, Ga);
}